// Round 11
// baseline (156.521 us; speedup 1.0000x reference)
//
#include <hip/hip_runtime.h>

#define NNODES 40000
#define NEDGES 640000
#define NFEAT  256
#define NHID   128

// ---- range partition geometry ----
#define RSHIFT 7                        // 128 nodes per range
#define RNODES 128
#define NR     313                      // ceil(40000/128)
#define CAPR   3000                     // LDS sort capacity; E[cnt]=2045, 21 sigma
#define PARTB  250                      // fill blocks
#define EPT    10
#define EPB    2560                     // edges per fill block
#define CAPB   32                       // slots per (range, block) cell; lambda=8.2
#define GEMM_BLOCKS (NNODES / 64)       // 625

// ---- workspace layout (bytes; ws_size = 256 MiB per R9 poison evidence) ----
#define SUP_OFF  0u                     // support bf16: 10,240,000
#define WT_OFF   10240000u              // Wt bf16: 65,536
#define CNT_OFF  10305536u              // cnt u16 [PARTB][NR]: 156,500 (reserve 160,000)
#define EBIN_OFF 10465536u              // ebin u64 [NR][PARTB][CAPB]: 20,032,000
#define WS_NEEDED (EBIN_OFF + (size_t)NR * PARTB * CAPB * 8)   // 30,497,536

typedef float floatx4 __attribute__((ext_vector_type(4)));
typedef __bf16 bf16x8 __attribute__((ext_vector_type(8)));
typedef unsigned short ushort8 __attribute__((ext_vector_type(8)));
union BfFrag { ushort8 s; bf16x8 b; };

__device__ __forceinline__ unsigned short f2bf(float f) {
    unsigned int u = __float_as_uint(f);
    u = (u + 0x7FFFu + ((u >> 16) & 1u)) >> 16;   // RNE
    return (unsigned short)u;
}

// decode 2x(2 bf16) -> float4
__device__ __forceinline__ float4 bf4(unsigned int lo, unsigned int hi) {
    float4 v;
    v.x = __uint_as_float(lo << 16);
    v.y = __uint_as_float(lo & 0xFFFF0000u);
    v.z = __uint_as_float(hi << 16);
    v.w = __uint_as_float(hi & 0xFFFF0000u);
    return v;
}

// ---------------------------------------------------------------------------
// K0: setup — Wt[h][k] = bf16(W[k][h]) only.
// ---------------------------------------------------------------------------
__global__ __launch_bounds__(256) void setup_wt(const float* __restrict__ W,
                                                unsigned short* __restrict__ Wt) {
    const int i = blockIdx.x * 256 + threadIdx.x;
    const int h = i >> 8;
    const int k = i & 255;
    Wt[i] = f2bf(W[k * NHID + h]);
}

// ---------------------------------------------------------------------------
// K1: GEMM (blocks [0,625)) || fill (blocks [625,875)).
// Fill: block pb OWNS cell [r][pb][0..32) for every range r (private 80KB
// region -> single-XCD, L2 write-combined). LDS u32 counter gives the slot,
// one direct 8B store per edge, then a contiguous 313-u16 count row.
// R10 BUG FIX: count writeout was `if (tid < NR)` with 256 threads — ranges
// 256..312 never written (garbage counts -> absmax 12.9). Now strided.
// ---------------------------------------------------------------------------
__global__ __launch_bounds__(256) void gemm_fill(const float* __restrict__ x,
                                                 const unsigned short* __restrict__ Wt,
                                                 unsigned short* __restrict__ support,
                                                 const int* __restrict__ ei,
                                                 const float* __restrict__ ew,
                                                 unsigned short* __restrict__ cnt,
                                                 unsigned long long* __restrict__ ebin) {
    const int tid = threadIdx.x;

    if (blockIdx.x >= GEMM_BLOCKS) {
        // ---- fill path ----
        __shared__ unsigned int ldscur[320];
        const int pb   = blockIdx.x - GEMM_BLOCKS;
        const int base = pb * EPB + tid;

        for (int i = tid; i < 320; i += 256) ldscur[i] = 0u;
        __syncthreads();

        int src[EPT], dst[EPT];
        float w[EPT];
        #pragma unroll
        for (int j = 0; j < EPT; j++) {
            const int e = base + j * 256;
            src[j] = ei[e];
            dst[j] = ei[NEDGES + e];
            w[j]   = ew[e];
        }
        #pragma unroll
        for (int j = 0; j < EPT; j++) {
            const int r = dst[j] >> RSHIFT;
            const unsigned int idx = atomicAdd(&ldscur[r], 1u);
            if (idx < CAPB) {
                const unsigned long long rec =
                    ((unsigned long long)f2bf(w[j]) << 32)
                  | ((unsigned long long)(dst[j] & (RNODES - 1)) << 16)
                  | (unsigned long long)(unsigned int)src[j];
                ebin[((size_t)r * PARTB + pb) * CAPB + idx] = rec;
            }
        }
        __syncthreads();

        for (int i = tid; i < NR; i += 256) {      // FIXED: strided, covers all 313
            unsigned int c = ldscur[i];
            if (c > CAPB) c = CAPB;
            cnt[(size_t)pb * NR + i] = (unsigned short)c;
        }
        return;
    }

    // ---- GEMM path (unchanged, proven) ----
    const int lane = tid & 63;
    const int wv   = tid >> 6;
    const int m    = lane & 15;
    const int quad = lane >> 4;
    const int node = blockIdx.x * 64 + wv * 16 + m;

    BfFrag afrag[8];
    const float* xrow = x + (size_t)node * NFEAT + quad * 8;
    #pragma unroll
    for (int ks = 0; ks < 8; ks++) {
        float4 f0 = *(const float4*)(xrow + ks * 32);
        float4 f1 = *(const float4*)(xrow + ks * 32 + 4);
        afrag[ks].s[0] = f2bf(f0.x); afrag[ks].s[1] = f2bf(f0.y);
        afrag[ks].s[2] = f2bf(f0.z); afrag[ks].s[3] = f2bf(f0.w);
        afrag[ks].s[4] = f2bf(f1.x); afrag[ks].s[5] = f2bf(f1.y);
        afrag[ks].s[6] = f2bf(f1.z); afrag[ks].s[7] = f2bf(f1.w);
    }

    floatx4 acc[8];
    #pragma unroll
    for (int nt = 0; nt < 8; nt++) acc[nt] = (floatx4){0.f, 0.f, 0.f, 0.f};

    #pragma unroll
    for (int nt = 0; nt < 8; nt++) {
        const unsigned short* wrow = Wt + (size_t)(nt * 16 + m) * NFEAT + quad * 8;
        #pragma unroll
        for (int ks = 0; ks < 8; ks++) {
            BfFrag bfrag;
            bfrag.s = *(const ushort8*)(wrow + ks * 32);
            acc[nt] = __builtin_amdgcn_mfma_f32_16x16x32_bf16(afrag[ks].b, bfrag.b,
                                                              acc[nt], 0, 0, 0);
        }
    }

    const int row0 = blockIdx.x * 64 + wv * 16 + quad * 4;
    #pragma unroll
    for (int nt = 0; nt < 8; nt++) {
        #pragma unroll
        for (int r = 0; r < 4; r++) {
            support[(size_t)(row0 + r) * NHID + nt * 16 + m] = f2bf(acc[nt][r]);
        }
    }
}

// ---------------------------------------------------------------------------
// K2: gather — one block (512 thr) per dst-range. Segmented input: thread
// t<250 owns cell [r][t][.]. Two passes over the segments (L2-hot on pass 2):
// histogram dl (native u32 LDS atomics) -> 7-pass scan -> scatter into
// dl-sorted srec -> R8's proven register walk (4 lanes/node, 32 hids/lane,
// zero fp atomics).
// ---------------------------------------------------------------------------
__global__ __launch_bounds__(512) void gather_range(
        const unsigned short* __restrict__ cnt,
        const unsigned long long* __restrict__ ebin,
        const unsigned short* __restrict__ support,
        const float* __restrict__ b,
        float* __restrict__ out) {
    __shared__ unsigned long long srec[CAPR];        // 24000 B, dl-sorted records
    __shared__ unsigned int hcnt[RNODES];
    __shared__ unsigned int hstart[RNODES + 1];
    __shared__ unsigned int sA[RNODES], sB[RNODES];

    const int r   = blockIdx.x;
    const int tid = threadIdx.x;

    unsigned int c_t = 0;
    const unsigned long long* seg =
        ebin + ((size_t)r * PARTB + (tid < PARTB ? tid : 0)) * CAPB;
    if (tid < PARTB) {
        c_t = cnt[(size_t)tid * NR + r];
        if (c_t > CAPB) c_t = CAPB;
    }
    if (tid < RNODES) hcnt[tid] = 0u;
    __syncthreads();

    // pass 1: histogram dl
    for (unsigned int k = 0; k < c_t; ++k)
        atomicAdd(&hcnt[(unsigned int)(seg[k] >> 16) & (RNODES - 1)], 1u);
    __syncthreads();

    // exclusive scan over 128 (Hillis-Steele, 7 passes)
    if (tid < RNODES) sA[tid] = (tid > 0) ? hcnt[tid - 1] : 0u;
    __syncthreads();
    unsigned int* cur = sA;
    unsigned int* nxt = sB;
    for (int off = 1; off < RNODES; off <<= 1) {
        if (tid < RNODES) nxt[tid] = cur[tid] + ((tid >= off) ? cur[tid - off] : 0u);
        __syncthreads();
        unsigned int* t = cur; cur = nxt; nxt = t;
    }
    if (tid < RNODES) hstart[tid] = cur[tid];
    if (tid == RNODES - 1) hstart[RNODES] = cur[RNODES - 1] + hcnt[RNODES - 1];
    __syncthreads();
    if (tid < RNODES) hcnt[tid] = hstart[tid];
    __syncthreads();

    // pass 2: scatter into sorted order (segments L2-hot)
    for (unsigned int k = 0; k < c_t; ++k) {
        const unsigned long long rec = seg[k];
        const unsigned int dl = (unsigned int)(rec >> 16) & (RNODES - 1);
        const unsigned int p  = atomicAdd(&hcnt[dl], 1u);
        if (p < CAPR) srec[p] = rec;
    }
    __syncthreads();

    // register-accumulated walk: 4 lanes per node, 32 hids per lane
    const int nl = tid >> 2;
    const int j  = tid & 3;
    unsigned int kb = hstart[nl];
    unsigned int ke = hstart[nl + 1];
    if (kb > CAPR) kb = CAPR;
    if (ke > CAPR) ke = CAPR;

    float acc[32];
    #pragma unroll
    for (int t = 0; t < 32; t++) acc[t] = 0.f;

    const uint4* sup4 = (const uint4*)support;       // 16 uint4 per row
    #pragma unroll 2
    for (unsigned int k = kb; k < ke; ++k) {
        const unsigned long long rec = srec[k];      // broadcast in 4-lane group
        const float w  = __uint_as_float(((unsigned int)(rec >> 32)) << 16);
        const int   sc = (int)(rec & 0xFFFFu);
        const uint4* rowp = sup4 + (size_t)sc * 16 + (j << 2);
        const uint4 u0 = rowp[0];
        const uint4 u1 = rowp[1];
        const uint4 u2 = rowp[2];
        const uint4 u3 = rowp[3];
        float4 v;
        v = bf4(u0.x, u0.y); acc[0] += w*v.x;  acc[1] += w*v.y;  acc[2] += w*v.z;  acc[3] += w*v.w;
        v = bf4(u0.z, u0.w); acc[4] += w*v.x;  acc[5] += w*v.y;  acc[6] += w*v.z;  acc[7] += w*v.w;
        v = bf4(u1.x, u1.y); acc[8] += w*v.x;  acc[9] += w*v.y;  acc[10] += w*v.z; acc[11] += w*v.w;
        v = bf4(u1.z, u1.w); acc[12] += w*v.x; acc[13] += w*v.y; acc[14] += w*v.z; acc[15] += w*v.w;
        v = bf4(u2.x, u2.y); acc[16] += w*v.x; acc[17] += w*v.y; acc[18] += w*v.z; acc[19] += w*v.w;
        v = bf4(u2.z, u2.w); acc[20] += w*v.x; acc[21] += w*v.y; acc[22] += w*v.z; acc[23] += w*v.w;
        v = bf4(u3.x, u3.y); acc[24] += w*v.x; acc[25] += w*v.y; acc[26] += w*v.z; acc[27] += w*v.w;
        v = bf4(u3.z, u3.w); acc[28] += w*v.x; acc[29] += w*v.y; acc[30] += w*v.z; acc[31] += w*v.w;
    }

    // epilogue: bias + relu + direct store
    const int node = r * RNODES + nl;
    if (node < NNODES) {
        const float4* b4p = (const float4*)b + (j << 3);
        float4*       o4  = (float4*)out + (size_t)node * (NHID / 4) + (j << 3);
        #pragma unroll
        for (int t = 0; t < 8; t++) {
            float4 bb = b4p[t];
            float4 v;
            v.x = fmaxf(acc[t * 4 + 0] + bb.x, 0.f);
            v.y = fmaxf(acc[t * 4 + 1] + bb.y, 0.f);
            v.z = fmaxf(acc[t * 4 + 2] + bb.z, 0.f);
            v.w = fmaxf(acc[t * 4 + 3] + bb.w, 0.f);
            o4[t] = v;
        }
    }
}

// ---------------------------------------------------------------------------
// Fallback path (ws too small): fp32 GEMM + atomic scatter
// ---------------------------------------------------------------------------
__global__ __launch_bounds__(256) void gemm_xw(const float* __restrict__ x,
                                               const float* __restrict__ W,
                                               float* __restrict__ support) {
    __shared__ float xs[64 * NFEAT];
    const int tid   = threadIdx.x;
    const int node0 = blockIdx.x * 64;

    const float4* xg  = (const float4*)(x + (size_t)node0 * NFEAT);
    float4*       xs4 = (float4*)xs;
    #pragma unroll
    for (int i = tid; i < 64 * (NFEAT / 4); i += 256) xs4[i] = xg[i];
    __syncthreads();

    const int hg = tid & 31;
    const int ng = tid >> 5;
    const float4* W4 = (const float4*)W;

    float4 acc[8];
    #pragma unroll
    for (int n = 0; n < 8; n++) acc[n] = make_float4(0.f, 0.f, 0.f, 0.f);

    #pragma unroll 4
    for (int k = 0; k < NFEAT; k++) {
        float4 w = W4[k * (NHID / 4) + hg];
        #pragma unroll
        for (int n = 0; n < 8; n++) {
            float xv = xs[(ng * 8 + n) * NFEAT + k];
            acc[n].x = fmaf(xv, w.x, acc[n].x);
            acc[n].y = fmaf(xv, w.y, acc[n].y);
            acc[n].z = fmaf(xv, w.z, acc[n].z);
            acc[n].w = fmaf(xv, w.w, acc[n].w);
        }
    }

    float4* out4 = (float4*)support;
    #pragma unroll
    for (int n = 0; n < 8; n++)
        out4[(size_t)(node0 + ng * 8 + n) * (NHID / 4) + hg] = acc[n];
}

__global__ __launch_bounds__(256) void scatter_edges(const int* __restrict__ ei,
                                                     const float* __restrict__ ew,
                                                     const float* __restrict__ support,
                                                     float* __restrict__ out) {
    const int tid  = threadIdx.x;
    const int lane = tid & 31;
    const int e    = blockIdx.x * 8 + (tid >> 5);
    const int   src = ei[e];
    const int   dst = ei[NEDGES + e];
    const float w   = ew[e];
    const float4* s4 = (const float4*)support;
    float4 v = s4[(size_t)src * (NHID / 4) + lane];
    float* o = out + (size_t)dst * NHID + lane * 4;
    atomicAdd(o + 0, v.x * w);
    atomicAdd(o + 1, v.y * w);
    atomicAdd(o + 2, v.z * w);
    atomicAdd(o + 3, v.w * w);
}

__global__ __launch_bounds__(256) void finalize(float* __restrict__ out,
                                                const float* __restrict__ b) {
    const int i = blockIdx.x * 256 + threadIdx.x;
    float4*       o4 = (float4*)out;
    const float4* b4 = (const float4*)b;
    float4 v  = o4[i];
    float4 bb = b4[i & 31];
    v.x = fmaxf(v.x + bb.x, 0.f);
    v.y = fmaxf(v.y + bb.y, 0.f);
    v.z = fmaxf(v.z + bb.z, 0.f);
    v.w = fmaxf(v.w + bb.w, 0.f);
    o4[i] = v;
}

extern "C" void kernel_launch(void* const* d_in, const int* in_sizes, int n_in,
                              void* d_out, int out_size, void* d_ws, size_t ws_size,
                              hipStream_t stream) {
    const float* x  = (const float*)d_in[0];
    const int*   ei = (const int*)d_in[1];
    const float* ew = (const float*)d_in[2];
    const float* W  = (const float*)d_in[3];
    const float* b  = (const float*)d_in[4];
    float*       out = (float*)d_out;

    char* ws = (char*)d_ws;

    if (ws_size >= WS_NEEDED) {
        unsigned short*     support = (unsigned short*)(ws + SUP_OFF);
        unsigned short*     Wt      = (unsigned short*)(ws + WT_OFF);
        unsigned short*     cnt     = (unsigned short*)(ws + CNT_OFF);
        unsigned long long* ebin    = (unsigned long long*)(ws + EBIN_OFF);

        setup_wt<<<128, 256, 0, stream>>>(W, Wt);
        gemm_fill<<<GEMM_BLOCKS + PARTB, 256, 0, stream>>>(
            x, Wt, support, ei, ew, cnt, ebin);
        gather_range<<<NR, 512, 0, stream>>>(cnt, ebin, support, b, out);
    } else {
        float* support = (float*)(ws + SUP_OFF);
        gemm_xw<<<NNODES / 64, 256, 0, stream>>>(x, W, support);
        hipMemsetAsync(d_out, 0, (size_t)out_size * sizeof(float), stream);
        scatter_edges<<<NEDGES / 8, 256, 0, stream>>>(ei, ew, support, out);
        finalize<<<out_size / 4 / 256, 256, 0, stream>>>(out, b);
    }
}